// Round 7
// baseline (132.561 us; speedup 1.0000x reference)
//
#include <hip/hip_runtime.h>
#include <stdint.h>

using u16 = unsigned short;
using u32 = unsigned int;
using u64 = unsigned long long;

typedef float f32x4 __attribute__((ext_vector_type(4)));
typedef __bf16 bf16x8 __attribute__((ext_vector_type(8)));

#define DEV static __device__ __forceinline__

// f32 -> bf16 round-to-nearest-even
DEV u16 f2bf(float f) {
  u32 u = __float_as_uint(f);
  u += 0x7FFFu + ((u >> 16) & 1u);
  return (u16)(u >> 16);
}

// async global->LDS, 16B per lane. LDS dest = wave-uniform base + lane*16.
DEV void gld16(const void* g, void* l) {
  __builtin_amdgcn_global_load_lds((__attribute__((address_space(1))) void*)g,
                                   (__attribute__((address_space(3))) void*)l,
                                   16, 0, 0);
}

// ---------------------------------------------------------------- converts
// merged: blocks [0,2048) convert x (f32->bf16); blocks [2048,3072) convert+
// transpose the four weight matrices.
__global__ void k_cvt(const float* __restrict__ x, u16* __restrict__ xb,
                      const float* __restrict__ w0, const float* __restrict__ w1,
                      const float* __restrict__ w2, const float* __restrict__ w3,
                      u16* __restrict__ t0, u16* __restrict__ t1,
                      u16* __restrict__ t2, u16* __restrict__ t3) {
  const int tid = threadIdx.x;
  if (blockIdx.x < 2048) {
    int i = (blockIdx.x * 256 + tid) * 8;
    float4 a = *(const float4*)&x[i];
    float4 b = *(const float4*)&x[i + 4];
    __align__(16) u16 o[8];
    o[0] = f2bf(a.x); o[1] = f2bf(a.y); o[2] = f2bf(a.z); o[3] = f2bf(a.w);
    o[4] = f2bf(b.x); o[5] = f2bf(b.y); o[6] = f2bf(b.z); o[7] = f2bf(b.w);
    *(uint4*)&xb[i] = *(const uint4*)o;
    return;
  }
  const int c = blockIdx.x - 2048;
  const int z = c >> 8, rem = c & 255;
  const float* w = z == 0 ? w0 : z == 1 ? w1 : z == 2 ? w2 : w3;
  u16* wt       = z == 0 ? t0 : z == 1 ? t1 : z == 2 ? t2 : t3;
  __shared__ __align__(16) float tile[64][68];
  const int k0 = (rem & 15) * 64, n0 = (rem >> 4) * 64;
#pragma unroll
  for (int i = 0; i < 4; ++i) {
    int cc = tid + i * 256;         // 1024 float4 chunks
    int kr = cc >> 4, col = (cc & 15) * 4;
    *(float4*)&tile[kr][col] = *(const float4*)&w[(size_t)(k0 + kr) * 1024 + n0 + col];
  }
  __syncthreads();
#pragma unroll
  for (int i = 0; i < 2; ++i) {
    int cc = tid + i * 256;         // 512 8xu16 chunks
    int nr = cc >> 3, kc = (cc & 7) * 8;
    __align__(16) u16 o[8];
#pragma unroll
    for (int j = 0; j < 8; ++j) o[j] = f2bf(tile[kc + j][nr]);
    *(uint4*)&wt[(size_t)(n0 + nr) * 1024 + k0 + kc] = *(const uint4*)o;
  }
}

// ---------------------------------------------------------------- GEMM core
// m97 structure: single-buffer LDS [128][32] bf16, XOR-swizzled via
// pre-swizzled global source; stage -> sync -> 16 MFMA -> sync per K-step.
DEV void gemm_mainloop(const u16* __restrict__ A, const u16* __restrict__ Bt,
                       int m0, int n0, u16* Asb, u16* Bsb, f32x4 (&acc)[4][4]) {
  const int tid = threadIdx.x;
  const int lane = tid & 63;
  const int wv = tid >> 6;
  const int wm = (wv >> 1) * 64, wn = (wv & 1) * 64;

#pragma unroll
  for (int i = 0; i < 4; ++i)
#pragma unroll
    for (int j = 0; j < 4; ++j) {
      f32x4 z = {0.f, 0.f, 0.f, 0.f};
      acc[i][j] = z;
    }

  const int c0 = wv * 64 + lane, c1 = c0 + 256;
  const int r0 = c0 >> 2, r1 = c1 >> 2;
  const int b0 = (c0 & 3) ^ (r0 & 3) ^ ((r0 >> 2) & 3);
  const int b1 = (c1 & 3) ^ (r1 & 3) ^ ((r1 >> 2) & 3);
  const u16* ga0 = A + (size_t)(m0 + r0) * 1024 + b0 * 8;
  const u16* ga1 = A + (size_t)(m0 + r1) * 1024 + b1 * 8;
  const u16* gb0 = Bt + (size_t)(n0 + r0) * 1024 + b0 * 8;
  const u16* gb1 = Bt + (size_t)(n0 + r1) * 1024 + b1 * 8;
  u16* la0 = Asb + (wv * 64) * 8;
  u16* la1 = Asb + (wv * 64 + 256) * 8;
  u16* lb0 = Bsb + (wv * 64) * 8;
  u16* lb1 = Bsb + (wv * 64 + 256) * 8;

  int aoff[4], boff[4];
#pragma unroll
  for (int f = 0; f < 4; ++f) {
    int ra = wm + f * 16 + (lane & 15);
    aoff[f] = ra * 32 + (((lane >> 4) ^ (ra & 3) ^ ((ra >> 2) & 3)) * 8);
    int rb = wn + f * 16 + (lane & 15);
    boff[f] = rb * 32 + (((lane >> 4) ^ (rb & 3) ^ ((rb >> 2) & 3)) * 8);
  }

  for (int kt = 0; kt < 32; ++kt) {
    const int k0 = kt * 32;
    gld16(ga0 + k0, la0);
    gld16(ga1 + k0, la1);
    gld16(gb0 + k0, lb0);
    gld16(gb1 + k0, lb1);
    __syncthreads();
    bf16x8 af[4], bfv[4];
#pragma unroll
    for (int f = 0; f < 4; ++f) af[f] = *(const bf16x8*)&Asb[aoff[f]];
#pragma unroll
    for (int f = 0; f < 4; ++f) bfv[f] = *(const bf16x8*)&Bsb[boff[f]];
#pragma unroll
    for (int i = 0; i < 4; ++i)
#pragma unroll
      for (int j = 0; j < 4; ++j)
        acc[i][j] = __builtin_amdgcn_mfma_f32_16x16x32_bf16(af[i], bfv[j], acc[i][j], 0, 0, 0);
    __syncthreads();
  }
}

// fused QKV projection: X[4096][1024]bf16 * Wt[1024][1024] -> Q/K/V [32][2048][64]bf16
__global__ __launch_bounds__(256) void k_gemm_qkv(
    const u16* __restrict__ X, const u16* __restrict__ Wq, const u16* __restrict__ Wk,
    const u16* __restrict__ Wv, u16* __restrict__ Q, u16* __restrict__ K,
    u16* __restrict__ V) {
  __shared__ __align__(16) u16 Asb[128 * 32];
  __shared__ __align__(16) u16 Bsb[128 * 32];
  const int nb = blockIdx.x, mb = blockIdx.y;
  const int proj = nb >> 3, n0 = (nb & 7) * 128;
  const u16* W = proj == 0 ? Wq : proj == 1 ? Wk : Wv;
  u16* Dst = proj == 0 ? Q : proj == 1 ? K : V;
  // fold 1/sqrt(64) * log2(e) into Q so attention can use exp2 directly
  const float scl = proj == 0 ? 0.125f * 1.4426950408889634f : 1.0f;
  f32x4 acc[4][4];
  gemm_mainloop(X, W, mb * 128, n0, Asb, Bsb, acc);
  const int lane = threadIdx.x & 63, wv = threadIdx.x >> 6;
  const int wm = (wv >> 1) * 64, wn = (wv & 1) * 64;
#pragma unroll
  for (int i = 0; i < 4; ++i)
#pragma unroll
    for (int j = 0; j < 4; ++j)
#pragma unroll
      for (int r = 0; r < 4; ++r) {
        int m = mb * 128 + wm + i * 16 + (lane >> 4) * 4 + r;   // global row (b*2048+s)
        int n = n0 + wn + j * 16 + (lane & 15);                 // 0..1023
        int b = m >> 11, s = m & 2047, h = n >> 6, d = n & 63;
        Dst[(size_t)((b * 16 + h) * 2048 + s) * 64 + d] = f2bf(acc[i][j][r] * scl);
      }
}

// output projection: AO[4096][1024]bf16 * WOt -> f32 out [4096][1024]
__global__ __launch_bounds__(256) void k_gemm_out(
    const u16* __restrict__ A, const u16* __restrict__ Wt, float* __restrict__ Out) {
  __shared__ __align__(16) u16 Asb[128 * 32];
  __shared__ __align__(16) u16 Bsb[128 * 32];
  const int nb = blockIdx.x, mb = blockIdx.y;
  f32x4 acc[4][4];
  gemm_mainloop(A, Wt, mb * 128, nb * 128, Asb, Bsb, acc);
  const int lane = threadIdx.x & 63, wv = threadIdx.x >> 6;
  const int wm = (wv >> 1) * 64, wn = (wv & 1) * 64;
#pragma unroll
  for (int i = 0; i < 4; ++i)
#pragma unroll
    for (int j = 0; j < 4; ++j)
#pragma unroll
      for (int r = 0; r < 4; ++r) {
        int m = mb * 128 + wm + i * 16 + (lane >> 4) * 4 + r;
        int n = nb * 128 + wn + j * 16 + (lane & 15);
        Out[(size_t)m * 1024 + n] = acc[i][j][r];
      }
}

// ---------------------------------------------------------------- V transpose
// V [32][2048][64] -> Vt' [32][64][2048] with sigma k-permutation applied
// within each 64-column block: sigma(k): bits [b5b4b3b2b1b0] -> [b4b3b2|b5|b1b0].
// Matches the in-register P fragment order from the swapped QK^T in k_attn.
__global__ void k_transpose_v(const u16* __restrict__ V, u16* __restrict__ Vt) {
  __shared__ __align__(16) u16 t[64][80];
  const int bh = blockIdx.y, s0 = blockIdx.x * 64;
  const int tid = threadIdx.x;
#pragma unroll
  for (int i = 0; i < 2; ++i) {
    int c = tid + i * 256;
    int sr = c >> 3, dc = (c & 7) * 8;
    *(uint4*)&t[sr][dc] = *(const uint4*)&V[((size_t)bh * 2048 + s0 + sr) * 64 + dc];
  }
  __syncthreads();
#pragma unroll
  for (int i = 0; i < 2; ++i) {
    int c = tid + i * 256;
    int dr = c >> 3, c7 = c & 7;
    __align__(8) u16 o[8];
#pragma unroll
    for (int j = 0; j < 8; ++j) o[j] = t[c7 * 8 + j][dr];
    int bp = ((c7 >> 1) & 1) * 32 + (c7 & 1) * 16 + ((c7 >> 2) & 1) * 4;
    u16* row = &Vt[((size_t)bh * 64 + dr) * 2048 + s0];
    *(u64*)&row[bp]     = *(const u64*)&o[0];
    *(u64*)&row[bp + 8] = *(const u64*)&o[4];
  }
}

// ---------------------------------------------------------------- attention
// 4-wave (256-thread) block: one (b,h) + complementary q-tile pair (j, 31-j).
// Waves 0-1 own tile A=j (32 q-rows each), waves 2-3 own tile B=31-j. Each
// wave processes TWO 16-row fragments (rf=0,1) -> 2x MFMA per phase and two
// independent softmax chains for ILP. One shared KV stream; all waves
// co-stage and hit every barrier. 32KB LDS -> 4 blocks/CU = 16 waves/CU.
__global__ __launch_bounds__(256, 4) void k_attn(
    const u16* __restrict__ Qg, const u16* __restrict__ Kg,
    const u16* __restrict__ Vtg, u16* __restrict__ Og) {
  __shared__ __align__(16) u16 Ks[2][64 * 64];
  __shared__ __align__(16) u16 Vs[2][64 * 64];
  const int tid = threadIdx.x, lane = tid & 63, wv = tid >> 6;
  const int lo = lane & 15, hi = lane >> 4;
  const int qsel = wv >> 1, wrow = (wv & 1) * 32;

  const int flat = blockIdx.y * 16 + blockIdx.x;
  const int xcd = flat & 7, slot = flat >> 3;       // 64 slots per XCD
  const int bh = xcd * 4 + (slot >> 4);             // 4 bh per XCD
  const int jp = slot & 15;

  const u16* Qb = Qg + (size_t)bh * 2048 * 64;
  const u16* Kb = Kg + (size_t)bh * 2048 * 64;
  const u16* Vb = Vtg + (size_t)bh * 64 * 2048;
  const int b = bh >> 4, h = bh & 15;

  const int nta = jp + 1, ntb = 32 - jp;
  const int q0 = (qsel ? (31 - jp) : jp) * 64;
  const int myNt = qsel ? ntb : nta;

  // Q fragments (scale * log2e folded in); B-operand of swapped QK^T
  bf16x8 qf[2][2];
#pragma unroll
  for (int rf = 0; rf < 2; ++rf)
#pragma unroll
    for (int kf = 0; kf < 2; ++kf)
      qf[rf][kf] = *(const bf16x8*)&Qb[(size_t)(q0 + wrow + rf * 16 + lo) * 64 +
                                       kf * 32 + hi * 8];

  f32x4 ao[2][4];
#pragma unroll
  for (int rf = 0; rf < 2; ++rf)
#pragma unroll
    for (int df = 0; df < 4; ++df) {
      f32x4 z = {0.f, 0.f, 0.f, 0.f};
      ao[rf][df] = z;
    }
  float m_run[2] = {-1e30f, -1e30f}, l_run[2] = {0.f, 0.f};

  // staging geometry: 512 chunks of 16B per 64x64 bf16 tile; 2 K + 2 V chunks
  // per thread (c0 = tid, c1 = tid + 256).
  const int c0 = tid, c1 = tid + 256;
  const int r0 = c0 >> 3, r1 = c1 >> 3;
  const int e0 = ((c0 & 7) ^ (r0 & 7)) * 8;
  const int e1 = ((c1 & 7) ^ (r1 & 7)) * 8;

  // prologue: stage tile 0 into buf 0
  gld16(Kb + (size_t)r0 * 64 + e0, &Ks[0][wv * 512]);
  gld16(Kb + (size_t)r1 * 64 + e1, &Ks[0][wv * 512 + 2048]);
  gld16(Vb + (size_t)r0 * 2048 + e0, &Vs[0][wv * 512]);
  gld16(Vb + (size_t)r1 * 2048 + e1, &Vs[0][wv * 512 + 2048]);
  __syncthreads();

#pragma unroll 1
  for (int t = 0; t < ntb; ++t) {
    const u16* Kc = Ks[t & 1];
    const u16* Vc = Vs[t & 1];
    if (t + 1 < ntb) {
      const int kn = (t + 1) * 64;
      u16* kd = Ks[(t + 1) & 1];
      u16* vd = Vs[(t + 1) & 1];
      gld16(Kb + (size_t)(kn + r0) * 64 + e0, kd + wv * 512);
      gld16(Kb + (size_t)(kn + r1) * 64 + e1, kd + wv * 512 + 2048);
      gld16(Vb + (size_t)r0 * 2048 + kn + e0, vd + wv * 512);
      gld16(Vb + (size_t)r1 * 2048 + kn + e1, vd + wv * 512 + 2048);
    }

    if (t < myNt) {
      // swapped QK^T: sc[rf][cf], lane q-row = q0+wrow+rf*16+lo,
      // k = t*64 + cf*16 + hi*4 + r. K frags shared across rf.
      f32x4 sc[2][4];
      __builtin_amdgcn_s_setprio(1);
#pragma unroll
      for (int cf = 0; cf < 4; ++cf) {
        f32x4 z = {0.f, 0.f, 0.f, 0.f};
        sc[0][cf] = z;
        sc[1][cf] = z;
#pragma unroll
        for (int kf = 0; kf < 2; ++kf) {
          int row = cf * 16 + lo;
          int blk = ((kf * 4 + hi) ^ (row & 7)) * 8;
          bf16x8 kfr = *(const bf16x8*)&Kc[row * 64 + blk];
          sc[0][cf] = __builtin_amdgcn_mfma_f32_16x16x32_bf16(kfr, qf[0][kf], sc[0][cf], 0, 0, 0);
          sc[1][cf] = __builtin_amdgcn_mfma_f32_16x16x32_bf16(kfr, qf[1][kf], sc[1][cf], 0, 0, 0);
        }
      }
      __builtin_amdgcn_s_setprio(0);

      // causal mask: only this q-tile's diagonal (last) tile
      if (t == myNt - 1) {
        const int kv0 = t * 64;
#pragma unroll
        for (int rf = 0; rf < 2; ++rf) {
          const int qq = q0 + wrow + rf * 16 + lo;
#pragma unroll
          for (int cf = 0; cf < 4; ++cf)
#pragma unroll
            for (int r = 0; r < 4; ++r) {
              int kk = kv0 + cf * 16 + hi * 4 + r;
              if (kk > qq) sc[rf][cf][r] = -1e30f;
            }
        }
      }

      // two independent online-softmax chains (in-lane; defer-max, merged cond)
      float mx[2];
#pragma unroll
      for (int rf = 0; rf < 2; ++rf) {
        float a0 = fmaxf(fmaxf(sc[rf][0][0], sc[rf][0][1]), fmaxf(sc[rf][0][2], sc[rf][0][3]));
        float a1 = fmaxf(fmaxf(sc[rf][1][0], sc[rf][1][1]), fmaxf(sc[rf][1][2], sc[rf][1][3]));
        float a2 = fmaxf(fmaxf(sc[rf][2][0], sc[rf][2][1]), fmaxf(sc[rf][2][2], sc[rf][2][3]));
        float a3 = fmaxf(fmaxf(sc[rf][3][0], sc[rf][3][1]), fmaxf(sc[rf][3][2], sc[rf][3][3]));
        float m = fmaxf(fmaxf(a0, a1), fmaxf(a2, a3));
        m = fmaxf(m, __shfl_xor(m, 16));
        m = fmaxf(m, __shfl_xor(m, 32));
        mx[rf] = m;
      }
      if (__any(fmaxf(mx[0] - m_run[0], mx[1] - m_run[1]) > 8.0f)) {
        const int base = lane & 48;
#pragma unroll
        for (int rf = 0; rf < 2; ++rf) {
          float mnew = fmaxf(m_run[rf], mx[rf]);
          float sclf = __builtin_amdgcn_exp2f(m_run[rf] - mnew);
#pragma unroll
          for (int r = 0; r < 4; ++r) {
            float s_r = __shfl(sclf, base + hi * 4 + r);
#pragma unroll
            for (int df = 0; df < 4; ++df) ao[rf][df][r] *= s_r;
          }
          l_run[rf] *= sclf;
          m_run[rf] = mnew;
        }
      }

      // P = exp2(sc - m), packed in-register into PV A-fragments (sigma order)
      bf16x8 pa[2][2];
      float psum[2];
#pragma unroll
      for (int rf = 0; rf < 2; ++rf) {
        float pp[4];
#pragma unroll
        for (int cf = 0; cf < 4; ++cf) {
          float p0 = __builtin_amdgcn_exp2f(sc[rf][cf][0] - m_run[rf]);
          float p1 = __builtin_amdgcn_exp2f(sc[rf][cf][1] - m_run[rf]);
          float p2 = __builtin_amdgcn_exp2f(sc[rf][cf][2] - m_run[rf]);
          float p3 = __builtin_amdgcn_exp2f(sc[rf][cf][3] - m_run[rf]);
          pp[cf] = (p0 + p1) + (p2 + p3);
          int j = (cf >> 1) * 4;
          bf16x8& pax = pa[rf][cf & 1];
          pax[j] = (__bf16)p0; pax[j + 1] = (__bf16)p1;
          pax[j + 2] = (__bf16)p2; pax[j + 3] = (__bf16)p3;
        }
        float ps = (pp[0] + pp[1]) + (pp[2] + pp[3]);
        ps += __shfl_xor(ps, 16);
        ps += __shfl_xor(ps, 32);
        l_run[rf] += ps;
        psum[rf] = ps;
      }
      (void)psum;

      // PV: V frags shared across rf
      __builtin_amdgcn_s_setprio(1);
#pragma unroll
      for (int df = 0; df < 4; ++df) {
#pragma unroll
        for (int kf = 0; kf < 2; ++kf) {
          int row = df * 16 + lo;
          int blk = ((kf * 4 + hi) ^ (row & 7)) * 8;
          bf16x8 vfr = *(const bf16x8*)&Vc[row * 64 + blk];
          ao[0][df] = __builtin_amdgcn_mfma_f32_16x16x32_bf16(pa[0][kf], vfr, ao[0][df], 0, 0, 0);
          ao[1][df] = __builtin_amdgcn_mfma_f32_16x16x32_bf16(pa[1][kf], vfr, ao[1][df], 0, 0, 0);
        }
      }
      __builtin_amdgcn_s_setprio(0);
    }

    // barrier: implicit vmcnt(0) drain makes next tile resident; also protects
    // the buffer being re-staged next iteration
    __syncthreads();
  }

  // epilogue: ao rows are q-offsets hi*4+r per rf; fetch each row's l via shuffle
  const int base = lane & 48;
#pragma unroll
  for (int rf = 0; rf < 2; ++rf) {
    float linv[4];
#pragma unroll
    for (int r = 0; r < 4; ++r) {
      float l_r = __shfl(l_run[rf], base + hi * 4 + r);
      linv[r] = 1.0f / l_r;
    }
#pragma unroll
    for (int df = 0; df < 4; ++df)
#pragma unroll
      for (int r = 0; r < 4; ++r) {
        int s = q0 + wrow + rf * 16 + hi * 4 + r;
        int d = df * 16 + lo;
        Og[((size_t)(b * 2048 + s)) * 1024 + h * 64 + d] = f2bf(ao[rf][df][r] * linv[r]);
      }
  }
}

// ---------------------------------------------------------------- launch
extern "C" void kernel_launch(void* const* d_in, const int* in_sizes, int n_in,
                              void* d_out, int out_size, void* d_ws, size_t ws_size,
                              hipStream_t stream) {
  const float* x = (const float*)d_in[0];
  const float* wq = (const float*)d_in[2];
  const float* wk = (const float*)d_in[3];
  const float* wv = (const float*)d_in[4];
  const float* wo = (const float*)d_in[5];

  char* ws = (char*)d_ws;
  u16* xb  = (u16*)(ws);                                   // 8 MiB  x bf16 [4096][1024]
  u16* wqt = (u16*)(ws + 8388608);                         // 2 MiB each, [N][K] bf16
  u16* wkt = (u16*)(ws + 8388608 + 2097152);
  u16* wvt = (u16*)(ws + 8388608 + 2 * 2097152);
  u16* wot = (u16*)(ws + 8388608 + 3 * 2097152);
  u16* qb  = (u16*)(ws + 16777216);                        // [32][2048][64] bf16
  u16* kb  = (u16*)(ws + 16777216 + 8388608);
  u16* vb  = (u16*)(ws + 16777216 + 2 * 8388608);
  u16* vt  = (u16*)(ws + 16777216 + 3 * 8388608);          // [32][64][2048] (sigma-permuted)
  u16* ao  = (u16*)(ws + 16777216 + 4 * 8388608);          // [4096][1024] bf16

  k_cvt<<<dim3(3072), dim3(256), 0, stream>>>(x, xb, wq, wk, wv, wo, wqt, wkt, wvt, wot);
  k_gemm_qkv<<<dim3(24, 32), dim3(256), 0, stream>>>(xb, wqt, wkt, wvt, qb, kb, vb);
  k_transpose_v<<<dim3(32, 32), dim3(256), 0, stream>>>(vb, vt);
  k_attn<<<dim3(16, 32), dim3(256), 0, stream>>>(qb, kb, vt, ao);
  k_gemm_out<<<dim3(8, 32), dim3(256), 0, stream>>>(ao, wot, (float*)d_out);
}

// Round 8
// 125.888 us; speedup vs baseline: 1.0530x; 1.0530x over previous
//
#include <hip/hip_runtime.h>
#include <stdint.h>

using u16 = unsigned short;
using u32 = unsigned int;
using u64 = unsigned long long;

typedef float f32x4 __attribute__((ext_vector_type(4)));
typedef __bf16 bf16x8 __attribute__((ext_vector_type(8)));

#define DEV static __device__ __forceinline__

// f32 -> bf16 round-to-nearest-even
DEV u16 f2bf(float f) {
  u32 u = __float_as_uint(f);
  u += 0x7FFFu + ((u >> 16) & 1u);
  return (u16)(u >> 16);
}

// async global->LDS, 16B per lane. LDS dest = wave-uniform base + lane*16.
DEV void gld16(const void* g, void* l) {
  __builtin_amdgcn_global_load_lds((__attribute__((address_space(1))) void*)g,
                                   (__attribute__((address_space(3))) void*)l,
                                   16, 0, 0);
}

// ---------------------------------------------------------------- converts
// merged: blocks [0,2048) convert x (f32->bf16); blocks [2048,3072) convert+
// transpose the four weight matrices.
__global__ void k_cvt(const float* __restrict__ x, u16* __restrict__ xb,
                      const float* __restrict__ w0, const float* __restrict__ w1,
                      const float* __restrict__ w2, const float* __restrict__ w3,
                      u16* __restrict__ t0, u16* __restrict__ t1,
                      u16* __restrict__ t2, u16* __restrict__ t3) {
  const int tid = threadIdx.x;
  if (blockIdx.x < 2048) {
    int i = (blockIdx.x * 256 + tid) * 8;
    float4 a = *(const float4*)&x[i];
    float4 b = *(const float4*)&x[i + 4];
    __align__(16) u16 o[8];
    o[0] = f2bf(a.x); o[1] = f2bf(a.y); o[2] = f2bf(a.z); o[3] = f2bf(a.w);
    o[4] = f2bf(b.x); o[5] = f2bf(b.y); o[6] = f2bf(b.z); o[7] = f2bf(b.w);
    *(uint4*)&xb[i] = *(const uint4*)o;
    return;
  }
  const int c = blockIdx.x - 2048;
  const int z = c >> 8, rem = c & 255;
  const float* w = z == 0 ? w0 : z == 1 ? w1 : z == 2 ? w2 : w3;
  u16* wt       = z == 0 ? t0 : z == 1 ? t1 : z == 2 ? t2 : t3;
  __shared__ __align__(16) float tile[64][68];
  const int k0 = (rem & 15) * 64, n0 = (rem >> 4) * 64;
#pragma unroll
  for (int i = 0; i < 4; ++i) {
    int cc = tid + i * 256;         // 1024 float4 chunks
    int kr = cc >> 4, col = (cc & 15) * 4;
    *(float4*)&tile[kr][col] = *(const float4*)&w[(size_t)(k0 + kr) * 1024 + n0 + col];
  }
  __syncthreads();
#pragma unroll
  for (int i = 0; i < 2; ++i) {
    int cc = tid + i * 256;         // 512 8xu16 chunks
    int nr = cc >> 3, kc = (cc & 7) * 8;
    __align__(16) u16 o[8];
#pragma unroll
    for (int j = 0; j < 8; ++j) o[j] = f2bf(tile[kc + j][nr]);
    *(uint4*)&wt[(size_t)(n0 + nr) * 1024 + k0 + kc] = *(const uint4*)o;
  }
}

// ---------------------------------------------------------------- GEMM core
// m97 structure: single-buffer LDS [128][32] bf16, XOR-swizzled via
// pre-swizzled global source; stage -> sync -> 16 MFMA -> sync per K-step.
DEV void gemm_mainloop(const u16* __restrict__ A, const u16* __restrict__ Bt,
                       int m0, int n0, u16* Asb, u16* Bsb, f32x4 (&acc)[4][4]) {
  const int tid = threadIdx.x;
  const int lane = tid & 63;
  const int wv = tid >> 6;
  const int wm = (wv >> 1) * 64, wn = (wv & 1) * 64;

#pragma unroll
  for (int i = 0; i < 4; ++i)
#pragma unroll
    for (int j = 0; j < 4; ++j) {
      f32x4 z = {0.f, 0.f, 0.f, 0.f};
      acc[i][j] = z;
    }

  const int c0 = wv * 64 + lane, c1 = c0 + 256;
  const int r0 = c0 >> 2, r1 = c1 >> 2;
  const int b0 = (c0 & 3) ^ (r0 & 3) ^ ((r0 >> 2) & 3);
  const int b1 = (c1 & 3) ^ (r1 & 3) ^ ((r1 >> 2) & 3);
  const u16* ga0 = A + (size_t)(m0 + r0) * 1024 + b0 * 8;
  const u16* ga1 = A + (size_t)(m0 + r1) * 1024 + b1 * 8;
  const u16* gb0 = Bt + (size_t)(n0 + r0) * 1024 + b0 * 8;
  const u16* gb1 = Bt + (size_t)(n0 + r1) * 1024 + b1 * 8;
  u16* la0 = Asb + (wv * 64) * 8;
  u16* la1 = Asb + (wv * 64 + 256) * 8;
  u16* lb0 = Bsb + (wv * 64) * 8;
  u16* lb1 = Bsb + (wv * 64 + 256) * 8;

  int aoff[4], boff[4];
#pragma unroll
  for (int f = 0; f < 4; ++f) {
    int ra = wm + f * 16 + (lane & 15);
    aoff[f] = ra * 32 + (((lane >> 4) ^ (ra & 3) ^ ((ra >> 2) & 3)) * 8);
    int rb = wn + f * 16 + (lane & 15);
    boff[f] = rb * 32 + (((lane >> 4) ^ (rb & 3) ^ ((rb >> 2) & 3)) * 8);
  }

  for (int kt = 0; kt < 32; ++kt) {
    const int k0 = kt * 32;
    gld16(ga0 + k0, la0);
    gld16(ga1 + k0, la1);
    gld16(gb0 + k0, lb0);
    gld16(gb1 + k0, lb1);
    __syncthreads();
    bf16x8 af[4], bfv[4];
#pragma unroll
    for (int f = 0; f < 4; ++f) af[f] = *(const bf16x8*)&Asb[aoff[f]];
#pragma unroll
    for (int f = 0; f < 4; ++f) bfv[f] = *(const bf16x8*)&Bsb[boff[f]];
#pragma unroll
    for (int i = 0; i < 4; ++i)
#pragma unroll
      for (int j = 0; j < 4; ++j)
        acc[i][j] = __builtin_amdgcn_mfma_f32_16x16x32_bf16(af[i], bfv[j], acc[i][j], 0, 0, 0);
    __syncthreads();
  }
}

// fused QKV projection: X[4096][1024]bf16 * Wt[1024][1024] -> Q/K/V [32][2048][64]bf16
__global__ __launch_bounds__(256) void k_gemm_qkv(
    const u16* __restrict__ X, const u16* __restrict__ Wq, const u16* __restrict__ Wk,
    const u16* __restrict__ Wv, u16* __restrict__ Q, u16* __restrict__ K,
    u16* __restrict__ V) {
  __shared__ __align__(16) u16 Asb[128 * 32];
  __shared__ __align__(16) u16 Bsb[128 * 32];
  const int nb = blockIdx.x, mb = blockIdx.y;
  const int proj = nb >> 3, n0 = (nb & 7) * 128;
  const u16* W = proj == 0 ? Wq : proj == 1 ? Wk : Wv;
  u16* Dst = proj == 0 ? Q : proj == 1 ? K : V;
  // fold 1/sqrt(64) * log2(e) into Q so attention can use exp2 directly
  const float scl = proj == 0 ? 0.125f * 1.4426950408889634f : 1.0f;
  f32x4 acc[4][4];
  gemm_mainloop(X, W, mb * 128, n0, Asb, Bsb, acc);
  const int lane = threadIdx.x & 63, wv = threadIdx.x >> 6;
  const int wm = (wv >> 1) * 64, wn = (wv & 1) * 64;
#pragma unroll
  for (int i = 0; i < 4; ++i)
#pragma unroll
    for (int j = 0; j < 4; ++j)
#pragma unroll
      for (int r = 0; r < 4; ++r) {
        int m = mb * 128 + wm + i * 16 + (lane >> 4) * 4 + r;   // global row (b*2048+s)
        int n = n0 + wn + j * 16 + (lane & 15);                 // 0..1023
        int b = m >> 11, s = m & 2047, h = n >> 6, d = n & 63;
        Dst[(size_t)((b * 16 + h) * 2048 + s) * 64 + d] = f2bf(acc[i][j][r] * scl);
      }
}

// output projection: AO[4096][1024]bf16 * WOt -> f32 out [4096][1024]
__global__ __launch_bounds__(256) void k_gemm_out(
    const u16* __restrict__ A, const u16* __restrict__ Wt, float* __restrict__ Out) {
  __shared__ __align__(16) u16 Asb[128 * 32];
  __shared__ __align__(16) u16 Bsb[128 * 32];
  const int nb = blockIdx.x, mb = blockIdx.y;
  f32x4 acc[4][4];
  gemm_mainloop(A, Wt, mb * 128, nb * 128, Asb, Bsb, acc);
  const int lane = threadIdx.x & 63, wv = threadIdx.x >> 6;
  const int wm = (wv >> 1) * 64, wn = (wv & 1) * 64;
#pragma unroll
  for (int i = 0; i < 4; ++i)
#pragma unroll
    for (int j = 0; j < 4; ++j)
#pragma unroll
      for (int r = 0; r < 4; ++r) {
        int m = mb * 128 + wm + i * 16 + (lane >> 4) * 4 + r;
        int n = nb * 128 + wn + j * 16 + (lane & 15);
        Out[(size_t)m * 1024 + n] = acc[i][j][r];
      }
}

// ---------------------------------------------------------------- V transpose
// V [32][2048][64] -> Vt' [32][64][2048] with sigma k-permutation applied
// within each 64-column block: sigma(k): bits [b5b4b3b2b1b0] -> [b4b3b2|b5|b1b0].
// Matches the in-register P fragment order from the swapped QK^T in k_attn.
__global__ void k_transpose_v(const u16* __restrict__ V, u16* __restrict__ Vt) {
  __shared__ __align__(16) u16 t[64][80];
  const int bh = blockIdx.y, s0 = blockIdx.x * 64;
  const int tid = threadIdx.x;
#pragma unroll
  for (int i = 0; i < 2; ++i) {
    int c = tid + i * 256;
    int sr = c >> 3, dc = (c & 7) * 8;
    *(uint4*)&t[sr][dc] = *(const uint4*)&V[((size_t)bh * 2048 + s0 + sr) * 64 + dc];
  }
  __syncthreads();
#pragma unroll
  for (int i = 0; i < 2; ++i) {
    int c = tid + i * 256;
    int dr = c >> 3, c7 = c & 7;
    __align__(8) u16 o[8];
#pragma unroll
    for (int j = 0; j < 8; ++j) o[j] = t[c7 * 8 + j][dr];
    int bp = ((c7 >> 1) & 1) * 32 + (c7 & 1) * 16 + ((c7 >> 2) & 1) * 4;
    u16* row = &Vt[((size_t)bh * 64 + dr) * 2048 + s0];
    *(u64*)&row[bp]     = *(const u64*)&o[0];
    *(u64*)&row[bp + 8] = *(const u64*)&o[4];
  }
}

// ---------------------------------------------------------------- attention
DEV void qk_tile(const u16* Kc, const bf16x8 (&qf)[2], int lo, int hi, f32x4 (&sc)[4]) {
#pragma unroll
  for (int cf = 0; cf < 4; ++cf) {
    f32x4 z = {0.f, 0.f, 0.f, 0.f};
    sc[cf] = z;
#pragma unroll
    for (int kf = 0; kf < 2; ++kf) {
      int row = cf * 16 + lo;
      int blk = ((kf * 4 + hi) ^ (row & 7)) * 8;
      bf16x8 kfr = *(const bf16x8*)&Kc[row * 64 + blk];
      sc[cf] = __builtin_amdgcn_mfma_f32_16x16x32_bf16(kfr, qf[kf], sc[cf], 0, 0, 0);
    }
  }
}

// online-softmax (in-lane, defer-max) + PV for one q-tile
DEV void sm_pv(f32x4 (&sc)[4], const u16* Vc, int lane, int lo, int hi,
               float& m_run, float& l_run, f32x4 (&ao)[4]) {
  float mx0 = fmaxf(fmaxf(sc[0][0], sc[0][1]), fmaxf(sc[0][2], sc[0][3]));
  float mx1 = fmaxf(fmaxf(sc[1][0], sc[1][1]), fmaxf(sc[1][2], sc[1][3]));
  float mx2 = fmaxf(fmaxf(sc[2][0], sc[2][1]), fmaxf(sc[2][2], sc[2][3]));
  float mx3 = fmaxf(fmaxf(sc[3][0], sc[3][1]), fmaxf(sc[3][2], sc[3][3]));
  float mx = fmaxf(fmaxf(mx0, mx1), fmaxf(mx2, mx3));
  mx = fmaxf(mx, __shfl_xor(mx, 16));
  mx = fmaxf(mx, __shfl_xor(mx, 32));

  // defer-max: rescale only when the max grew by > 8 (log2 units)
  if (__any(mx > m_run + 8.0f)) {
    float mnew = fmaxf(m_run, mx);
    float sclf = __builtin_amdgcn_exp2f(m_run - mnew);
    const int base = lane & 48;
#pragma unroll
    for (int r = 0; r < 4; ++r) {
      float s_r = __shfl(sclf, base + hi * 4 + r);
#pragma unroll
      for (int df = 0; df < 4; ++df) ao[df][r] *= s_r;
    }
    l_run *= sclf;
    m_run = mnew;
  }

  // P = exp2(sc - m_run), packed in-register into PV A-fragments (sigma order)
  float pp[4];
  bf16x8 pa0, pa1;
#pragma unroll
  for (int cf = 0; cf < 4; ++cf) {
    float p0 = __builtin_amdgcn_exp2f(sc[cf][0] - m_run);
    float p1 = __builtin_amdgcn_exp2f(sc[cf][1] - m_run);
    float p2 = __builtin_amdgcn_exp2f(sc[cf][2] - m_run);
    float p3 = __builtin_amdgcn_exp2f(sc[cf][3] - m_run);
    pp[cf] = (p0 + p1) + (p2 + p3);
    bf16x8& pa = (cf & 1) ? pa1 : pa0;
    int j = (cf >> 1) * 4;
    pa[j] = (__bf16)p0; pa[j + 1] = (__bf16)p1;
    pa[j + 2] = (__bf16)p2; pa[j + 3] = (__bf16)p3;
  }
  float psum = (pp[0] + pp[1]) + (pp[2] + pp[3]);
  psum += __shfl_xor(psum, 16);
  psum += __shfl_xor(psum, 32);
  l_run += psum;

  __builtin_amdgcn_s_setprio(1);
#pragma unroll
  for (int df = 0; df < 4; ++df) {
#pragma unroll
    for (int kf = 0; kf < 2; ++kf) {
      int row = df * 16 + lo;
      int blk = ((kf * 4 + hi) ^ (row & 7)) * 8;
      bf16x8 vfr = *(const bf16x8*)&Vc[row * 64 + blk];
      ao[df] = __builtin_amdgcn_mfma_f32_16x16x32_bf16(kf == 0 ? pa0 : pa1, vfr,
                                                       ao[df], 0, 0, 0);
    }
  }
  __builtin_amdgcn_s_setprio(0);
}

// one (b,h, 64-row q-tile) per block; 4 waves x 16 rows; every wave computes
// every iteration (no idle waves). Grid 1024 = 4 blocks/CU, all co-resident.
// Placement model (validated R5/R6): XCD = flat&7; within an XCD, slot=flat>>3
// round-robins 32 CUs, so CU c hosts slots {c, c+32, c+64, c+96}. Remap gives
// those four slots qt = {c, 31-c, c^16, 31-(c^16)} -> per-CU work = 66
// tile-units for every CU (perfect balance), and bh = xcd*4 + quarter keeps
// 4 bh per XCD (KV 2MB, L2-resident). Bijective over (bh, qt).
__global__ __launch_bounds__(256) void k_attn(
    const u16* __restrict__ Qg, const u16* __restrict__ Kg,
    const u16* __restrict__ Vtg, u16* __restrict__ Og) {
  __shared__ __align__(16) u16 Ks[2][64 * 64];
  __shared__ __align__(16) u16 Vs[2][64 * 64];
  const int tid = threadIdx.x, lane = tid & 63, wv = tid >> 6;
  const int lo = lane & 15, hi = lane >> 4;

  const int flat = blockIdx.y * 32 + blockIdx.x;
  const int xcd = flat & 7, slot = flat >> 3;       // slot 0..127 per XCD
  const int q4 = slot >> 5, cu = slot & 31;         // quarter, CU index
  const int bh = xcd * 4 + q4;                      // 4 bh per XCD
  const int cux = (q4 & 2) ? (cu ^ 16) : cu;
  const int qt = (q4 & 1) ? (31 - cux) : cux;       // balanced per-CU qt set

  const u16* Qb = Qg + (size_t)bh * 2048 * 64;
  const u16* Kb = Kg + (size_t)bh * 2048 * 64;
  const u16* Vb = Vtg + (size_t)bh * 64 * 2048;
  const int b = bh >> 4, h = bh & 15;

  const int q0 = qt * 64;
  const int nt = qt + 1;
  const int qq = q0 + wv * 16 + lo;

  // Q fragments (scale * log2e folded in); B-operand of swapped QK^T
  bf16x8 qf[2];
#pragma unroll
  for (int kf = 0; kf < 2; ++kf)
    qf[kf] = *(const bf16x8*)&Qb[(size_t)(q0 + wv * 16 + lo) * 64 + kf * 32 + hi * 8];

  f32x4 ao[4];
#pragma unroll
  for (int df = 0; df < 4; ++df) {
    f32x4 z = {0.f, 0.f, 0.f, 0.f};
    ao[df] = z;
  }
  float m_run = -1e30f, l_run = 0.f;

  // staging geometry: 512 chunks of 16B per 64x64 bf16 tile (128B rows, 8 blocks)
  const int c0 = wv * 64 + lane, c1 = c0 + 256;
  const int r0 = c0 >> 3, r1 = c1 >> 3;
  const int e0 = ((c0 & 7) ^ (r0 & 7)) * 8;
  const int e1 = ((c1 & 7) ^ (r1 & 7)) * 8;

  // prologue: stage tile 0 into buf 0
  gld16(Kb + (size_t)r0 * 64 + e0, &Ks[0][wv * 512]);
  gld16(Kb + (size_t)r1 * 64 + e1, &Ks[0][wv * 512 + 2048]);
  gld16(Vb + (size_t)r0 * 2048 + e0, &Vs[0][wv * 512]);
  gld16(Vb + (size_t)r1 * 2048 + e1, &Vs[0][wv * 512 + 2048]);
  __syncthreads();

#pragma unroll 1
  for (int t = 0; t < nt; ++t) {
    const u16* Kc = Ks[t & 1];
    const u16* Vc = Vs[t & 1];
    if (t + 1 < nt) {
      const int kn = (t + 1) * 64;
      u16* kd = Ks[(t + 1) & 1];
      u16* vd = Vs[(t + 1) & 1];
      gld16(Kb + (size_t)(kn + r0) * 64 + e0, kd + wv * 512);
      gld16(Kb + (size_t)(kn + r1) * 64 + e1, kd + wv * 512 + 2048);
      gld16(Vb + (size_t)r0 * 2048 + kn + e0, vd + wv * 512);
      gld16(Vb + (size_t)r1 * 2048 + kn + e1, vd + wv * 512 + 2048);
    }

    f32x4 sc[4];
    __builtin_amdgcn_s_setprio(1);
    qk_tile(Kc, qf, lo, hi, sc);
    __builtin_amdgcn_s_setprio(0);

    // causal mask: only the diagonal (last) tile
    if (t == nt - 1) {
      const int kv0 = t * 64;
#pragma unroll
      for (int cf = 0; cf < 4; ++cf)
#pragma unroll
        for (int r = 0; r < 4; ++r) {
          int kk = kv0 + cf * 16 + hi * 4 + r;
          if (kk > qq) sc[cf][r] = -1e30f;
        }
    }

    sm_pv(sc, Vc, lane, lo, hi, m_run, l_run, ao);

    // barrier: implicit vmcnt(0) drain makes next tile resident; also protects
    // the buffer being re-staged next iteration
    __syncthreads();
  }

  // epilogue: ao rows are q-offsets hi*4+r; fetch each row's l via shuffle
  float linv[4];
  const int base = lane & 48;
#pragma unroll
  for (int r = 0; r < 4; ++r) {
    float l_r = __shfl(l_run, base + hi * 4 + r);
    linv[r] = 1.0f / l_r;
  }
#pragma unroll
  for (int df = 0; df < 4; ++df)
#pragma unroll
    for (int r = 0; r < 4; ++r) {
      int s = q0 + wv * 16 + hi * 4 + r;
      int d = df * 16 + lo;
      Og[((size_t)(b * 2048 + s)) * 1024 + h * 64 + d] = f2bf(ao[df][r] * linv[r]);
    }
}

// ---------------------------------------------------------------- launch
extern "C" void kernel_launch(void* const* d_in, const int* in_sizes, int n_in,
                              void* d_out, int out_size, void* d_ws, size_t ws_size,
                              hipStream_t stream) {
  const float* x = (const float*)d_in[0];
  const float* wq = (const float*)d_in[2];
  const float* wk = (const float*)d_in[3];
  const float* wv = (const float*)d_in[4];
  const float* wo = (const float*)d_in[5];

  char* ws = (char*)d_ws;
  u16* xb  = (u16*)(ws);                                   // 8 MiB  x bf16 [4096][1024]
  u16* wqt = (u16*)(ws + 8388608);                         // 2 MiB each, [N][K] bf16
  u16* wkt = (u16*)(ws + 8388608 + 2097152);
  u16* wvt = (u16*)(ws + 8388608 + 2 * 2097152);
  u16* wot = (u16*)(ws + 8388608 + 3 * 2097152);
  u16* qb  = (u16*)(ws + 16777216);                        // [32][2048][64] bf16
  u16* kb  = (u16*)(ws + 16777216 + 8388608);
  u16* vb  = (u16*)(ws + 16777216 + 2 * 8388608);
  u16* vt  = (u16*)(ws + 16777216 + 3 * 8388608);          // [32][64][2048] (sigma-permuted)
  u16* ao  = (u16*)(ws + 16777216 + 4 * 8388608);          // [4096][1024] bf16

  k_cvt<<<dim3(3072), dim3(256), 0, stream>>>(x, xb, wq, wk, wv, wo, wqt, wkt, wvt, wot);
  k_gemm_qkv<<<dim3(24, 32), dim3(256), 0, stream>>>(xb, wqt, wkt, wvt, qb, kb, vb);
  k_transpose_v<<<dim3(32, 32), dim3(256), 0, stream>>>(vb, vt);
  k_attn<<<dim3(32, 32), dim3(256), 0, stream>>>(qb, kb, vt, ao);
  k_gemm_out<<<dim3(8, 32), dim3(256), 0, stream>>>(ao, wot, (float*)d_out);
}

// Round 9
// 118.909 us; speedup vs baseline: 1.1148x; 1.0587x over previous
//
#include <hip/hip_runtime.h>
#include <stdint.h>

using u16 = unsigned short;
using u32 = unsigned int;
using u64 = unsigned long long;

typedef float f32x4 __attribute__((ext_vector_type(4)));
typedef __bf16 bf16x8 __attribute__((ext_vector_type(8)));

#define DEV static __device__ __forceinline__

// f32 -> bf16 round-to-nearest-even
DEV u16 f2bf(float f) {
  u32 u = __float_as_uint(f);
  u += 0x7FFFu + ((u >> 16) & 1u);
  return (u16)(u >> 16);
}

// async global->LDS, 16B per lane. LDS dest = wave-uniform base + lane*16.
DEV void gld16(const void* g, void* l) {
  __builtin_amdgcn_global_load_lds((__attribute__((address_space(1))) void*)g,
                                   (__attribute__((address_space(3))) void*)l,
                                   16, 0, 0);
}

// ---------------------------------------------------------------- converts
// merged: blocks [0,2048) convert x (f32->bf16); blocks [2048,3072) convert+
// transpose the four weight matrices.
__global__ void k_cvt(const float* __restrict__ x, u16* __restrict__ xb,
                      const float* __restrict__ w0, const float* __restrict__ w1,
                      const float* __restrict__ w2, const float* __restrict__ w3,
                      u16* __restrict__ t0, u16* __restrict__ t1,
                      u16* __restrict__ t2, u16* __restrict__ t3) {
  const int tid = threadIdx.x;
  if (blockIdx.x < 2048) {
    int i = (blockIdx.x * 256 + tid) * 8;
    float4 a = *(const float4*)&x[i];
    float4 b = *(const float4*)&x[i + 4];
    __align__(16) u16 o[8];
    o[0] = f2bf(a.x); o[1] = f2bf(a.y); o[2] = f2bf(a.z); o[3] = f2bf(a.w);
    o[4] = f2bf(b.x); o[5] = f2bf(b.y); o[6] = f2bf(b.z); o[7] = f2bf(b.w);
    *(uint4*)&xb[i] = *(const uint4*)o;
    return;
  }
  const int c = blockIdx.x - 2048;
  const int z = c >> 8, rem = c & 255;
  const float* w = z == 0 ? w0 : z == 1 ? w1 : z == 2 ? w2 : w3;
  u16* wt       = z == 0 ? t0 : z == 1 ? t1 : z == 2 ? t2 : t3;
  __shared__ __align__(16) float tile[64][68];
  const int k0 = (rem & 15) * 64, n0 = (rem >> 4) * 64;
#pragma unroll
  for (int i = 0; i < 4; ++i) {
    int cc = tid + i * 256;         // 1024 float4 chunks
    int kr = cc >> 4, col = (cc & 15) * 4;
    *(float4*)&tile[kr][col] = *(const float4*)&w[(size_t)(k0 + kr) * 1024 + n0 + col];
  }
  __syncthreads();
#pragma unroll
  for (int i = 0; i < 2; ++i) {
    int cc = tid + i * 256;         // 512 8xu16 chunks
    int nr = cc >> 3, kc = (cc & 7) * 8;
    __align__(16) u16 o[8];
#pragma unroll
    for (int j = 0; j < 8; ++j) o[j] = f2bf(tile[kc + j][nr]);
    *(uint4*)&wt[(size_t)(n0 + nr) * 1024 + k0 + kc] = *(const uint4*)o;
  }
}

// ---------------------------------------------------------------- GEMM core
// counted-vmcnt pipeline (T3/T4): 3 LDS buffers, depth-2 prefetch, ONE raw
// s_barrier per K-step, vmcnt(4) steady (never drain to 0 mid-loop).
// Per wave per K-step: 4 global_load_lds ops.
DEV void gemm_mainloop(const u16* __restrict__ A, const u16* __restrict__ Bt,
                       int m0, int n0, u16* Asb, u16* Bsb, f32x4 (&acc)[4][4]) {
  const int tid = threadIdx.x;
  const int lane = tid & 63;
  const int wv = tid >> 6;
  const int wm = (wv >> 1) * 64, wn = (wv & 1) * 64;

#pragma unroll
  for (int i = 0; i < 4; ++i)
#pragma unroll
    for (int j = 0; j < 4; ++j) {
      f32x4 z = {0.f, 0.f, 0.f, 0.f};
      acc[i][j] = z;
    }

  const int c0 = wv * 64 + lane, c1 = c0 + 256;
  const int r0 = c0 >> 2, r1 = c1 >> 2;
  const int b0 = (c0 & 3) ^ (r0 & 3) ^ ((r0 >> 2) & 3);
  const int b1 = (c1 & 3) ^ (r1 & 3) ^ ((r1 >> 2) & 3);
  const u16* ga0 = A + (size_t)(m0 + r0) * 1024 + b0 * 8;
  const u16* ga1 = A + (size_t)(m0 + r1) * 1024 + b1 * 8;
  const u16* gb0 = Bt + (size_t)(n0 + r0) * 1024 + b0 * 8;
  const u16* gb1 = Bt + (size_t)(n0 + r1) * 1024 + b1 * 8;
  const int da0 = (wv * 64) * 8, da1 = (wv * 64 + 256) * 8;

  int aoff[4], boff[4];
#pragma unroll
  for (int f = 0; f < 4; ++f) {
    int ra = wm + f * 16 + (lane & 15);
    aoff[f] = ra * 32 + (((lane >> 4) ^ (ra & 3) ^ ((ra >> 2) & 3)) * 8);
    int rb = wn + f * 16 + (lane & 15);
    boff[f] = rb * 32 + (((lane >> 4) ^ (rb & 3) ^ ((rb >> 2) & 3)) * 8);
  }

  // prologue: stage kt=0 -> buf0, kt=1 -> buf1 (8 VMEM ops outstanding/wave)
#pragma unroll
  for (int p = 0; p < 2; ++p) {
    const int k0 = p * 32, bo = p * 4096;
    gld16(ga0 + k0, Asb + bo + da0);
    gld16(ga1 + k0, Asb + bo + da1);
    gld16(gb0 + k0, Bsb + bo + da0);
    gld16(gb1 + k0, Bsb + bo + da1);
  }

#pragma unroll 1
  for (int kt = 0; kt < 32; ++kt) {
    // entry outstanding: loads(kt) + loads(kt+1) = 8 -> wait oldest 4 done
    if (kt < 31) asm volatile("s_waitcnt vmcnt(4)" ::: "memory");
    else         asm volatile("s_waitcnt vmcnt(0)" ::: "memory");
    __builtin_amdgcn_s_barrier();
    __builtin_amdgcn_sched_barrier(0);

    // stage kt+2 into buf (kt+2)%3 == (kt-1)%3 (freed by the barrier above)
    if (kt + 2 < 32) {
      const int k0 = (kt + 2) * 32, bo = ((kt + 2) % 3) * 4096;
      gld16(ga0 + k0, Asb + bo + da0);
      gld16(ga1 + k0, Asb + bo + da1);
      gld16(gb0 + k0, Bsb + bo + da0);
      gld16(gb1 + k0, Bsb + bo + da1);
    }

    const int bo = (kt % 3) * 4096;
    bf16x8 af[4], bfv[4];
#pragma unroll
    for (int f = 0; f < 4; ++f) af[f] = *(const bf16x8*)&Asb[bo + aoff[f]];
#pragma unroll
    for (int f = 0; f < 4; ++f) bfv[f] = *(const bf16x8*)&Bsb[bo + boff[f]];
#pragma unroll
    for (int i = 0; i < 4; ++i)
#pragma unroll
      for (int j = 0; j < 4; ++j)
        acc[i][j] = __builtin_amdgcn_mfma_f32_16x16x32_bf16(af[i], bfv[j], acc[i][j], 0, 0, 0);
  }
}

// fused QKV projection: X[4096][1024]bf16 * Wt[1024][1024] -> Q/K/V [32][2048][64]bf16
__global__ __launch_bounds__(256) void k_gemm_qkv(
    const u16* __restrict__ X, const u16* __restrict__ Wq, const u16* __restrict__ Wk,
    const u16* __restrict__ Wv, u16* __restrict__ Q, u16* __restrict__ K,
    u16* __restrict__ V) {
  __shared__ __align__(16) u16 Asb[3 * 4096];
  __shared__ __align__(16) u16 Bsb[3 * 4096];
  const int nb = blockIdx.x, mb = blockIdx.y;
  const int proj = nb >> 3, n0 = (nb & 7) * 128;
  const u16* W = proj == 0 ? Wq : proj == 1 ? Wk : Wv;
  u16* Dst = proj == 0 ? Q : proj == 1 ? K : V;
  // fold 1/sqrt(64) * log2(e) into Q so attention can use exp2 directly
  const float scl = proj == 0 ? 0.125f * 1.4426950408889634f : 1.0f;
  f32x4 acc[4][4];
  gemm_mainloop(X, W, mb * 128, n0, Asb, Bsb, acc);
  const int lane = threadIdx.x & 63, wv = threadIdx.x >> 6;
  const int wm = (wv >> 1) * 64, wn = (wv & 1) * 64;
#pragma unroll
  for (int i = 0; i < 4; ++i)
#pragma unroll
    for (int j = 0; j < 4; ++j)
#pragma unroll
      for (int r = 0; r < 4; ++r) {
        int m = mb * 128 + wm + i * 16 + (lane >> 4) * 4 + r;   // global row (b*2048+s)
        int n = n0 + wn + j * 16 + (lane & 15);                 // 0..1023
        int b = m >> 11, s = m & 2047, h = n >> 6, d = n & 63;
        Dst[(size_t)((b * 16 + h) * 2048 + s) * 64 + d] = f2bf(acc[i][j][r] * scl);
      }
}

// output projection: AO[4096][1024]bf16 * WOt -> f32 out [4096][1024]
__global__ __launch_bounds__(256) void k_gemm_out(
    const u16* __restrict__ A, const u16* __restrict__ Wt, float* __restrict__ Out) {
  __shared__ __align__(16) u16 Asb[3 * 4096];
  __shared__ __align__(16) u16 Bsb[3 * 4096];
  const int nb = blockIdx.x, mb = blockIdx.y;
  f32x4 acc[4][4];
  gemm_mainloop(A, Wt, mb * 128, nb * 128, Asb, Bsb, acc);
  const int lane = threadIdx.x & 63, wv = threadIdx.x >> 6;
  const int wm = (wv >> 1) * 64, wn = (wv & 1) * 64;
#pragma unroll
  for (int i = 0; i < 4; ++i)
#pragma unroll
    for (int j = 0; j < 4; ++j)
#pragma unroll
      for (int r = 0; r < 4; ++r) {
        int m = mb * 128 + wm + i * 16 + (lane >> 4) * 4 + r;
        int n = nb * 128 + wn + j * 16 + (lane & 15);
        Out[(size_t)m * 1024 + n] = acc[i][j][r];
      }
}

// ---------------------------------------------------------------- V transpose
// V [32][2048][64] -> Vt' [32][64][2048] with sigma k-permutation applied
// within each 64-column block: sigma(k): bits [b5b4b3b2b1b0] -> [b4b3b2|b5|b1b0].
// Matches the in-register P fragment order from the swapped QK^T in k_attn.
__global__ void k_transpose_v(const u16* __restrict__ V, u16* __restrict__ Vt) {
  __shared__ __align__(16) u16 t[64][80];
  const int bh = blockIdx.y, s0 = blockIdx.x * 64;
  const int tid = threadIdx.x;
#pragma unroll
  for (int i = 0; i < 2; ++i) {
    int c = tid + i * 256;
    int sr = c >> 3, dc = (c & 7) * 8;
    *(uint4*)&t[sr][dc] = *(const uint4*)&V[((size_t)bh * 2048 + s0 + sr) * 64 + dc];
  }
  __syncthreads();
#pragma unroll
  for (int i = 0; i < 2; ++i) {
    int c = tid + i * 256;
    int dr = c >> 3, c7 = c & 7;
    __align__(8) u16 o[8];
#pragma unroll
    for (int j = 0; j < 8; ++j) o[j] = t[c7 * 8 + j][dr];
    int bp = ((c7 >> 1) & 1) * 32 + (c7 & 1) * 16 + ((c7 >> 2) & 1) * 4;
    u16* row = &Vt[((size_t)bh * 64 + dr) * 2048 + s0];
    *(u64*)&row[bp]     = *(const u64*)&o[0];
    *(u64*)&row[bp + 8] = *(const u64*)&o[4];
  }
}

// ---------------------------------------------------------------- attention
DEV void qk_tile(const u16* Kc, const bf16x8 (&qf)[2], int lo, int hi, f32x4 (&sc)[4]) {
#pragma unroll
  for (int cf = 0; cf < 4; ++cf) {
    f32x4 z = {0.f, 0.f, 0.f, 0.f};
    sc[cf] = z;
#pragma unroll
    for (int kf = 0; kf < 2; ++kf) {
      int row = cf * 16 + lo;
      int blk = ((kf * 4 + hi) ^ (row & 7)) * 8;
      bf16x8 kfr = *(const bf16x8*)&Kc[row * 64 + blk];
      sc[cf] = __builtin_amdgcn_mfma_f32_16x16x32_bf16(kfr, qf[kf], sc[cf], 0, 0, 0);
    }
  }
}

// online-softmax (in-lane, defer-max) + PV for one q-tile
DEV void sm_pv(f32x4 (&sc)[4], const u16* Vc, int lane, int lo, int hi,
               float& m_run, float& l_run, f32x4 (&ao)[4]) {
  float mx0 = fmaxf(fmaxf(sc[0][0], sc[0][1]), fmaxf(sc[0][2], sc[0][3]));
  float mx1 = fmaxf(fmaxf(sc[1][0], sc[1][1]), fmaxf(sc[1][2], sc[1][3]));
  float mx2 = fmaxf(fmaxf(sc[2][0], sc[2][1]), fmaxf(sc[2][2], sc[2][3]));
  float mx3 = fmaxf(fmaxf(sc[3][0], sc[3][1]), fmaxf(sc[3][2], sc[3][3]));
  float mx = fmaxf(fmaxf(mx0, mx1), fmaxf(mx2, mx3));
  mx = fmaxf(mx, __shfl_xor(mx, 16));
  mx = fmaxf(mx, __shfl_xor(mx, 32));

  // defer-max: rescale only when the max grew by > 8 (log2 units)
  if (__any(mx > m_run + 8.0f)) {
    float mnew = fmaxf(m_run, mx);
    float sclf = __builtin_amdgcn_exp2f(m_run - mnew);
    const int base = lane & 48;
#pragma unroll
    for (int r = 0; r < 4; ++r) {
      float s_r = __shfl(sclf, base + hi * 4 + r);
#pragma unroll
      for (int df = 0; df < 4; ++df) ao[df][r] *= s_r;
    }
    l_run *= sclf;
    m_run = mnew;
  }

  // P = exp2(sc - m_run), packed in-register into PV A-fragments (sigma order)
  float pp[4];
  bf16x8 pa0, pa1;
#pragma unroll
  for (int cf = 0; cf < 4; ++cf) {
    float p0 = __builtin_amdgcn_exp2f(sc[cf][0] - m_run);
    float p1 = __builtin_amdgcn_exp2f(sc[cf][1] - m_run);
    float p2 = __builtin_amdgcn_exp2f(sc[cf][2] - m_run);
    float p3 = __builtin_amdgcn_exp2f(sc[cf][3] - m_run);
    pp[cf] = (p0 + p1) + (p2 + p3);
    bf16x8& pa = (cf & 1) ? pa1 : pa0;
    int j = (cf >> 1) * 4;
    pa[j] = (__bf16)p0; pa[j + 1] = (__bf16)p1;
    pa[j + 2] = (__bf16)p2; pa[j + 3] = (__bf16)p3;
  }
  float psum = (pp[0] + pp[1]) + (pp[2] + pp[3]);
  psum += __shfl_xor(psum, 16);
  psum += __shfl_xor(psum, 32);
  l_run += psum;

  __builtin_amdgcn_s_setprio(1);
#pragma unroll
  for (int df = 0; df < 4; ++df) {
#pragma unroll
    for (int kf = 0; kf < 2; ++kf) {
      int row = df * 16 + lo;
      int blk = ((kf * 4 + hi) ^ (row & 7)) * 8;
      bf16x8 vfr = *(const bf16x8*)&Vc[row * 64 + blk];
      ao[df] = __builtin_amdgcn_mfma_f32_16x16x32_bf16(kf == 0 ? pa0 : pa1, vfr,
                                                       ao[df], 0, 0, 0);
    }
  }
  __builtin_amdgcn_s_setprio(0);
}

// 8-wave (512-thread) block: one (b,h) + complementary q-tile pair (j, 31-j).
// Waves 0-3 own tile A=j, waves 4-7 own tile B=31-j; every block = 33 tile-
// computes (placement-independent balance; R6-validated). Counted-vmcnt
// pipeline: 4 LDS buffers, depth-3 prefetch, ONE raw s_barrier per tile,
// vmcnt(4) steady (T4: never drain to 0 mid-loop). Buffer (t+3)%4 == (t-1)%4
// is freed by the barrier at the top of iter t.
__global__ __launch_bounds__(512) void k_attn(
    const u16* __restrict__ Qg, const u16* __restrict__ Kg,
    const u16* __restrict__ Vtg, u16* __restrict__ Og) {
  __shared__ __align__(16) u16 Ks[4][64 * 64];
  __shared__ __align__(16) u16 Vs[4][64 * 64];
  const int tid = threadIdx.x, lane = tid & 63, wv = tid >> 6;
  const int lo = lane & 15, hi = lane >> 4;
  const int w4 = wv & 3, qsel = wv >> 2;

  const int flat = blockIdx.y * 16 + blockIdx.x;
  const int xcd = flat & 7, slot = flat >> 3;       // 64 slots per XCD
  const int bh = xcd * 4 + (slot >> 4);             // 4 bh per XCD
  const int jp = slot & 15;

  const u16* Qb = Qg + (size_t)bh * 2048 * 64;
  const u16* Kb = Kg + (size_t)bh * 2048 * 64;
  const u16* Vb = Vtg + (size_t)bh * 64 * 2048;
  const int b = bh >> 4, h = bh & 15;

  const int nta = jp + 1, ntb = 32 - jp;            // ntb >= 17
  const int q0 = (qsel ? (31 - jp) : jp) * 64;
  const int myNt = qsel ? ntb : nta;
  const int qq = q0 + w4 * 16 + lo;

  // Q fragments (scale * log2e folded in); B-operand of swapped QK^T
  bf16x8 qf[2];
#pragma unroll
  for (int kf = 0; kf < 2; ++kf)
    qf[kf] = *(const bf16x8*)&Qb[(size_t)(q0 + w4 * 16 + lo) * 64 + kf * 32 + hi * 8];

  f32x4 ao[4];
#pragma unroll
  for (int df = 0; df < 4; ++df) {
    f32x4 z = {0.f, 0.f, 0.f, 0.f};
    ao[df] = z;
  }
  float m_run = -1e30f, l_run = 0.f;

  // staging geometry: 512 chunks of 16B per 64x64 tile; 1 K + 1 V chunk/thread
  const int r0 = tid >> 3;
  const int e0 = ((tid & 7) ^ (r0 & 7)) * 8;

  // prologue: stage tiles 0,1,2 (6 VMEM ops outstanding per wave)
#pragma unroll
  for (int p = 0; p < 3; ++p) {
    gld16(Kb + (size_t)(p * 64 + r0) * 64 + e0, &Ks[p][wv * 512]);
    gld16(Vb + (size_t)r0 * 2048 + p * 64 + e0, &Vs[p][wv * 512]);
  }

#pragma unroll 1
  for (int t = 0; t < ntb; ++t) {
    // entry outstanding: loads(t),(t+1),(t+2) = 6 -> wait oldest pair done
    if (t + 2 < ntb)      asm volatile("s_waitcnt vmcnt(4)" ::: "memory");
    else if (t + 1 < ntb) asm volatile("s_waitcnt vmcnt(2)" ::: "memory");
    else                  asm volatile("s_waitcnt vmcnt(0)" ::: "memory");
    __builtin_amdgcn_s_barrier();
    __builtin_amdgcn_sched_barrier(0);

    // stage t+3 into buf (t+3)&3 == (t-1)&3 (freed by the barrier above)
    if (t + 3 < ntb) {
      const int kn = (t + 3) * 64;
      gld16(Kb + (size_t)(kn + r0) * 64 + e0, &Ks[(t + 3) & 3][wv * 512]);
      gld16(Vb + (size_t)r0 * 2048 + kn + e0, &Vs[(t + 3) & 3][wv * 512]);
    }

    if (t < myNt) {
      const u16* Kc = Ks[t & 3];
      const u16* Vc = Vs[t & 3];
      f32x4 sc[4];
      __builtin_amdgcn_s_setprio(1);
      qk_tile(Kc, qf, lo, hi, sc);
      __builtin_amdgcn_s_setprio(0);

      // causal mask: only this q-tile's diagonal (last) tile
      if (t == myNt - 1) {
        const int kv0 = t * 64;
#pragma unroll
        for (int cf = 0; cf < 4; ++cf)
#pragma unroll
          for (int r = 0; r < 4; ++r) {
            int kk = kv0 + cf * 16 + hi * 4 + r;
            if (kk > qq) sc[cf][r] = -1e30f;
          }
      }

      sm_pv(sc, Vc, lane, lo, hi, m_run, l_run, ao);
    }
  }

  // epilogue: ao rows are q-offsets hi*4+r; fetch each row's l via shuffle
  float linv[4];
  const int base = lane & 48;
#pragma unroll
  for (int r = 0; r < 4; ++r) {
    float l_r = __shfl(l_run, base + hi * 4 + r);
    linv[r] = 1.0f / l_r;
  }
#pragma unroll
  for (int df = 0; df < 4; ++df)
#pragma unroll
    for (int r = 0; r < 4; ++r) {
      int s = q0 + w4 * 16 + hi * 4 + r;
      int d = df * 16 + lo;
      Og[((size_t)(b * 2048 + s)) * 1024 + h * 64 + d] = f2bf(ao[df][r] * linv[r]);
    }
}

// ---------------------------------------------------------------- launch
extern "C" void kernel_launch(void* const* d_in, const int* in_sizes, int n_in,
                              void* d_out, int out_size, void* d_ws, size_t ws_size,
                              hipStream_t stream) {
  const float* x = (const float*)d_in[0];
  const float* wq = (const float*)d_in[2];
  const float* wk = (const float*)d_in[3];
  const float* wv = (const float*)d_in[4];
  const float* wo = (const float*)d_in[5];

  char* ws = (char*)d_ws;
  u16* xb  = (u16*)(ws);                                   // 8 MiB  x bf16 [4096][1024]
  u16* wqt = (u16*)(ws + 8388608);                         // 2 MiB each, [N][K] bf16
  u16* wkt = (u16*)(ws + 8388608 + 2097152);
  u16* wvt = (u16*)(ws + 8388608 + 2 * 2097152);
  u16* wot = (u16*)(ws + 8388608 + 3 * 2097152);
  u16* qb  = (u16*)(ws + 16777216);                        // [32][2048][64] bf16
  u16* kb  = (u16*)(ws + 16777216 + 8388608);
  u16* vb  = (u16*)(ws + 16777216 + 2 * 8388608);
  u16* vt  = (u16*)(ws + 16777216 + 3 * 8388608);          // [32][64][2048] (sigma-permuted)
  u16* ao  = (u16*)(ws + 16777216 + 4 * 8388608);          // [4096][1024] bf16

  k_cvt<<<dim3(3072), dim3(256), 0, stream>>>(x, xb, wq, wk, wv, wo, wqt, wkt, wvt, wot);
  k_gemm_qkv<<<dim3(24, 32), dim3(256), 0, stream>>>(xb, wqt, wkt, wvt, qb, kb, vb);
  k_transpose_v<<<dim3(32, 32), dim3(256), 0, stream>>>(vb, vt);
  k_attn<<<dim3(16, 32), dim3(512), 0, stream>>>(qb, kb, vt, ao);
  k_gemm_out<<<dim3(8, 32), dim3(256), 0, stream>>>(ao, wot, (float*)d_out);
}